// Round 9
// baseline (464.555 us; speedup 1.0000x reference)
//
#include <hip/hip_runtime.h>
#include <hip/hip_bf16.h>
#include <cstddef>

// MHAttention forward, MI355X/gfx950.
// Dtype contract (R0-R3): inputs fp32 (toks, W*, b*; masks int32), OUTPUT fp32.
// Internals: bf16 MFMA fragments, fp32 accumulation.
// R8 -> R9: attn pinned at ~298us across 3 schedules; FETCH 136MB vs ~50MB unique
// => qtile-fastest grid spread every bh across all XCDs -> 24MB K/V working set
// thrashed the 4MB per-XCD L2 -> every hot-loop K/V access at L3 latency.
// R9: 1-D grid with bh FASTEST (gid = qtile*48 + bh): same-bh blocks share an XCD
// (gid%8 round-robin heuristic), per-XCD K/V = 3MB fits L2. Also folded log2e
// into scale+mask so softmax uses raw v_exp_f32 (exp2), trimming the VALU chain.

typedef __bf16 bf16_8 __attribute__((ext_vector_type(8)));
typedef float f32x4 __attribute__((ext_vector_type(4)));
typedef short s16x4 __attribute__((ext_vector_type(4)));

#define HID 768
#define NHEADS 12
#define HD 64
#define BATCH 4
#define SEQ 2048
#define LOG2E 1.44269504f
#define NEGBIG2 (-1.44269504e31f)  // -1e31 * log2e, exp2 -> 0
#define SCALE2 0.18033688f         // 0.125 * log2e

#define QSTR 72  // ldsQ row stride (elems): 36 dwords -> 2-way only (free)
#define PSTR 40  // ldsP row stride (elems): 20 dwords -> 2-way only (free)

static __device__ __forceinline__ f32x4 mfma16x16x32(bf16_8 a, bf16_8 b, f32x4 c) {
  return __builtin_amdgcn_mfma_f32_16x16x32_bf16(a, b, c, 0, 0, 0);
}

static __device__ __forceinline__ float fast_exp2(float x) {
#if __has_builtin(__builtin_amdgcn_exp2f)
  return __builtin_amdgcn_exp2f(x);
#else
  return __expf(x * 0.69314718f);
#endif
}

static __device__ __forceinline__ s16x4 pack_bf16x4(f32x4 p) {
  s16x4 o;
#pragma unroll
  for (int i = 0; i < 4; ++i) {
    __bf16 b = (__bf16)p[i];
    o[i] = __builtin_bit_cast(short, b);
  }
  return o;
}

static __device__ __forceinline__ bf16_8 cvt_a_frag(const float* p) {
  f32x4 af0 = *(const f32x4*)p;
  f32x4 af1 = *(const f32x4*)(p + 4);
  bf16_8 a;
  a[0] = (__bf16)af0[0]; a[1] = (__bf16)af0[1];
  a[2] = (__bf16)af0[2]; a[3] = (__bf16)af0[3];
  a[4] = (__bf16)af1[0]; a[5] = (__bf16)af1[1];
  a[6] = (__bf16)af1[2]; a[7] = (__bf16)af1[3];
  return a;
}

// ---------- mask -> additive kadd2 (0 or -1e31*log2e), fp32, global ----------
__global__ __launch_bounds__(256) void mask_kadd(const int* __restrict__ masks,
                                                 float* __restrict__ kaddG) {
  int i = blockIdx.x * 256 + threadIdx.x;
  kaddG[i] = masks[i] ? 0.0f : NEGBIG2;
}

// ---------- 3x 768x768 transpose + fp32->bf16, one launch (z picks matrix) ----------
__global__ __launch_bounds__(256) void transpose768x3(const float* __restrict__ Wq,
                                                      const float* __restrict__ Wk,
                                                      const float* __restrict__ Wv,
                                                      __bf16* __restrict__ WtBase) {
  const float* in = blockIdx.z == 0 ? Wq : (blockIdx.z == 1 ? Wk : Wv);
  __bf16* out = WtBase + (size_t)blockIdx.z * HID * HID;
  __shared__ __bf16 tile[32][33];
  int bx = blockIdx.x * 32, by = blockIdx.y * 32;
  int tx = threadIdx.x, ty = threadIdx.y;  // block (32,8)
#pragma unroll
  for (int r = 0; r < 32; r += 8)
    tile[ty + r][tx] = (__bf16)in[(size_t)(by + ty + r) * HID + bx + tx];
  __syncthreads();
#pragma unroll
  for (int r = 0; r < 32; r += 8)
    out[(size_t)(bx + ty + r) * HID + by + tx] = tile[tx][ty + r];
}

// ---------- K+V projection fused: one wave -> 32 rows x 64 cols, both K and V ----------
__global__ __launch_bounds__(64) void proj_kv(const float* __restrict__ toks,
                                              const __bf16* __restrict__ WtK,
                                              const float* __restrict__ bk,
                                              const __bf16* __restrict__ WtV,
                                              const float* __restrict__ bv,
                                              __bf16* __restrict__ Kout,
                                              __bf16* __restrict__ Vtout,
                                              int head0, int hm) {
  int lane = threadIdx.x, l16 = lane & 15, quad = lane >> 4;
  int m0 = blockIdx.x * 32;
  int hl = blockIdx.y, h = head0 + hl;
  const float* arow0 = toks + (size_t)(m0 + l16) * HID + quad * 8;
  const float* arow1 = arow0 + (size_t)16 * HID;
  const __bf16* bKrow = WtK + (size_t)(h * 64 + l16) * HID + quad * 8;
  const __bf16* bVrow = WtV + (size_t)(h * 64 + l16) * HID + quad * 8;
  f32x4 zero = {0.f, 0.f, 0.f, 0.f};
  f32x4 aK[2][4], aV[2][4];
#pragma unroll
  for (int g = 0; g < 2; ++g)
#pragma unroll
    for (int t = 0; t < 4; ++t) { aK[g][t] = zero; aV[g][t] = zero; }
  for (int kk = 0; kk < HID; kk += 32) {
    bf16_8 a0 = cvt_a_frag(arow0 + kk);
    bf16_8 a1 = cvt_a_frag(arow1 + kk);
#pragma unroll
    for (int t = 0; t < 4; ++t) {
      bf16_8 bkf = *(const bf16_8*)(bKrow + (size_t)t * 16 * HID + kk);
      bf16_8 bvf = *(const bf16_8*)(bVrow + (size_t)t * 16 * HID + kk);
      aK[0][t] = mfma16x16x32(a0, bkf, aK[0][t]);
      aK[1][t] = mfma16x16x32(a1, bkf, aK[1][t]);
      aV[0][t] = mfma16x16x32(a0, bvf, aV[0][t]);
      aV[1][t] = mfma16x16x32(a1, bvf, aV[1][t]);
    }
  }
#pragma unroll
  for (int g = 0; g < 2; ++g)
#pragma unroll
    for (int t = 0; t < 4; ++t) {
      int d = t * 16 + l16;
      float bnK = bk[h * 64 + d];
      float bnV = bv[h * 64 + d];
#pragma unroll
      for (int r = 0; r < 4; ++r) {
        int m = m0 + g * 16 + quad * 4 + r;
        int b = m >> 11;
        int s = m & (SEQ - 1);
        Kout[(((size_t)b * hm + hl) * SEQ + s) * HD + d] = (__bf16)(aK[g][t][r] + bnK);
        Vtout[(((size_t)b * hm + hl) * HD + d) * SEQ + s] = (__bf16)(aV[g][t][r] + bnV);
      }
    }
}

// ---------- fused Q-proj + flash attention ----------
// ONE wave per (b, h, 32-query tile); 2 x 16-q subtiles share K/V frags.
// Tier A (hm==NHEADS): 1-D grid, gid = qtile*48 + bh -> same-bh blocks on one
// XCD (K/V stay L2-resident). Tier B (hm==1): old 3-D grid decode.
// S^T = K*Q^T, b64 P stores -> b128 A-frag reads, no barriers (single wave),
// register prefetch of next K frags + mask vec.
__global__ __launch_bounds__(64) void attn_fused(const float* __restrict__ toks,
                                                 const __bf16* __restrict__ WtQ,
                                                 const float* __restrict__ bq,
                                                 const __bf16* __restrict__ Kbuf,
                                                 const __bf16* __restrict__ Vtbuf,
                                                 const float* __restrict__ kaddG,
                                                 float* __restrict__ out,
                                                 int head0, int hm) {
  __shared__ __align__(16) __bf16 ldsQ[2][16 * QSTR];  // 4608 B
  __shared__ __align__(16) __bf16 ldsP[2][16 * PSTR];  // 2560 B
  int lane = threadIdx.x, l16 = lane & 15, quad = lane >> 4;
  int bz, hl, q0;
  if (hm == NHEADS) {  // Tier A: swizzled 1-D grid
    int gid = blockIdx.x;
    int bh = gid % (BATCH * NHEADS);
    q0 = (gid / (BATCH * NHEADS)) * 32;
    bz = bh / NHEADS;
    hl = bh % NHEADS;
  } else {  // Tier B
    bz = blockIdx.z;
    hl = 0;
    q0 = blockIdx.x * 32;
  }
  int h = head0 + hl;
  const float* kb = kaddG + (size_t)bz * SEQ;
  f32x4 zero = {0.f, 0.f, 0.f, 0.f};

  // --- Q projection: both 16-row subtiles ---
#pragma unroll
  for (int qt = 0; qt < 2; ++qt) {
    const float* arow = toks + ((size_t)bz * SEQ + q0 + qt * 16 + l16) * HID + quad * 8;
    const __bf16* brow = WtQ + (size_t)(h * 64 + l16) * HID + quad * 8;
    f32x4 qa[4] = {zero, zero, zero, zero};
    for (int kk = 0; kk < HID; kk += 32) {
      bf16_8 a = cvt_a_frag(arow + kk);
#pragma unroll
      for (int t = 0; t < 4; ++t)
        qa[t] = mfma16x16x32(a, *(const bf16_8*)(brow + (size_t)t * 16 * HID + kk), qa[t]);
    }
#pragma unroll
    for (int t = 0; t < 4; ++t) {
      float bn = bq[h * 64 + t * 16 + l16];
#pragma unroll
      for (int r = 0; r < 4; ++r)
        ldsQ[qt][(quad * 4 + r) * QSTR + t * 16 + l16] = (__bf16)(qa[t][r] + bn);
    }
  }
  // Q frags (RAW dep orders this): lane holds Q[q=l16][d=quad*8+j]
  bf16_8 aq[2][2];
#pragma unroll
  for (int qt = 0; qt < 2; ++qt) {
    aq[qt][0] = *(const bf16_8*)(&ldsQ[qt][l16 * QSTR + quad * 8]);
    aq[qt][1] = *(const bf16_8*)(&ldsQ[qt][l16 * QSTR + 32 + quad * 8]);
  }
  // query-row activity (q = l16 per subtile): 1 -> normal, 0 -> all-zero logits (= ref)
  float actq[2];
  actq[0] = (kb[q0 + l16] == 0.0f) ? 1.0f : 0.0f;
  actq[1] = (kb[q0 + 16 + l16] == 0.0f) ? 1.0f : 0.0f;

  const __bf16* Kb = Kbuf + ((size_t)bz * hm + hl) * SEQ * HD;
  const __bf16* Vb = Vtbuf + ((size_t)bz * hm + hl) * HD * SEQ;
  float lsum[2] = {0.f, 0.f};
  f32x4 acc[2][4];
#pragma unroll
  for (int qt = 0; qt < 2; ++qt)
#pragma unroll
    for (int dt = 0; dt < 4; ++dt) acc[qt][dt] = zero;

  const int NKT = SEQ / 32;
  // preload kt=0: K A-frags (lane: K[key=blk*16+l16][d=quad*8+j (+32)]) + mask vec
  bf16_8 kf[2][2];
  f32x4 ck[2];
  {
    const __bf16* kp0 = Kb + (size_t)l16 * HD + quad * 8;
    const __bf16* kp1 = Kb + (size_t)(16 + l16) * HD + quad * 8;
    kf[0][0] = *(const bf16_8*)kp0; kf[0][1] = *(const bf16_8*)(kp0 + 32);
    kf[1][0] = *(const bf16_8*)kp1; kf[1][1] = *(const bf16_8*)(kp1 + 32);
    ck[0] = *(const f32x4*)(kb + quad * 4);
    ck[1] = *(const f32x4*)(kb + 16 + quad * 4);
  }
  for (int kt = 0; kt < NKT; ++kt) {
    int j0 = kt * 32;
    int jn = (kt + 1 < NKT) ? j0 + 32 : 0;  // wrap: avoids OOB, values unused
    // V B-frags for THIS iteration (used at body bottom -> latency hidden)
    bf16_8 vf[4];
#pragma unroll
    for (int dt = 0; dt < 4; ++dt)
      vf[dt] = *(const bf16_8*)(Vb + (size_t)(dt * 16 + l16) * SEQ + j0 + quad * 8);
    // prefetch NEXT iteration's K frags + mask vec
    bf16_8 kfn[2][2];
    f32x4 ckn[2];
    {
      const __bf16* kp0 = Kb + (size_t)(jn + l16) * HD + quad * 8;
      const __bf16* kp1 = Kb + (size_t)(jn + 16 + l16) * HD + quad * 8;
      kfn[0][0] = *(const bf16_8*)kp0; kfn[0][1] = *(const bf16_8*)(kp0 + 32);
      kfn[1][0] = *(const bf16_8*)kp1; kfn[1][1] = *(const bf16_8*)(kp1 + 32);
      ckn[0] = *(const f32x4*)(kb + jn + quad * 4);
      ckn[1] = *(const f32x4*)(kb + jn + 16 + quad * 4);
    }
    // QK -> exp2 -> pack -> P store (both subtiles)
#pragma unroll
    for (int qt = 0; qt < 2; ++qt) {
#pragma unroll
      for (int blk = 0; blk < 2; ++blk) {
        f32x4 st = mfma16x16x32(kf[blk][1], aq[qt][1],
                                mfma16x16x32(kf[blk][0], aq[qt][0], zero));
        f32x4 p;
#pragma unroll
        for (int r = 0; r < 4; ++r) {
          // logits pre-scaled by log2e: masked key -> -1.44e31, exp2 -> 0.
          // inactive q: actq=0 -> logit 0 -> uniform (= ref).
          float v = actq[qt] * fmaf(st[r], SCALE2, ck[blk][r]);
          p[r] = fast_exp2(v);
        }
        lsum[qt] += p[0] + p[1] + p[2] + p[3];
        // P[q=l16][key=blk*16+quad*4 .. +4] -> one b64 store
        *(s16x4*)(&ldsP[qt][l16 * PSTR + blk * 16 + quad * 4]) = pack_bf16x4(p);
      }
    }
    // PV: A-frag = P row q=l16, k=quad*8+j (RAW dep on stores above orders this)
#pragma unroll
    for (int qt = 0; qt < 2; ++qt) {
      bf16_8 ap = *(const bf16_8*)(&ldsP[qt][l16 * PSTR + quad * 8]);
#pragma unroll
      for (int dt = 0; dt < 4; ++dt)
        acc[qt][dt] = mfma16x16x32(ap, vf[dt], acc[qt][dt]);
    }
    kf[0][0] = kfn[0][0]; kf[0][1] = kfn[0][1];
    kf[1][0] = kfn[1][0]; kf[1][1] = kfn[1][1];
    ck[0] = ckn[0]; ck[1] = ckn[1];
  }

  // denominator: per-lane partials at (q=l16, key-quad=quad) -> sum quads
#pragma unroll
  for (int qt = 0; qt < 2; ++qt) {
    float s = lsum[qt];
    s += __shfl_xor(s, 16);
    s += __shfl_xor(s, 32);
    float linv = 1.0f / s;
#pragma unroll
    for (int r = 0; r < 4; ++r) {
      float lr = __shfl(linv, quad * 4 + r);  // linv for q = quad*4+r
#pragma unroll
      for (int dt = 0; dt < 4; ++dt)
        out[((size_t)bz * SEQ + q0 + qt * 16 + quad * 4 + r) * HID + h * HD + dt * 16 + l16] =
            acc[qt][dt][r] * lr;
    }
  }
}

extern "C" void kernel_launch(void* const* d_in, const int* in_sizes, int n_in,
                              void* d_out, int out_size, void* d_ws, size_t ws_size,
                              hipStream_t stream) {
  (void)in_sizes; (void)n_in; (void)out_size;
  const float* toks = (const float*)d_in[0];
  const int* masks = (const int*)d_in[1];
  const float* Wq = (const float*)d_in[2];
  const float* bq = (const float*)d_in[3];
  const float* Wk = (const float*)d_in[4];
  const float* bk = (const float*)d_in[5];
  const float* Wv = (const float*)d_in[6];
  const float* bv = (const float*)d_in[7];
  char* ws = (char*)d_ws;
  const size_t KADD_B = (size_t)BATCH * SEQ * 4;
  const size_t WT_B = (size_t)HID * HID * 2;
  const size_t KV_FULL_B = (size_t)BATCH * NHEADS * SEQ * HD * 2;
  const size_t KV_HEAD_B = (size_t)BATCH * SEQ * HD * 2;
  const size_t TIER_A_NEED = KADD_B + 3 * WT_B + 2 * KV_FULL_B;  // ~28.7 MB
  float* kaddG = (float*)(ws);
  __bf16* WtQ = (__bf16*)(ws + KADD_B + 0 * WT_B);
  __bf16* WtK = (__bf16*)(ws + KADD_B + 1 * WT_B);
  __bf16* WtV = (__bf16*)(ws + KADD_B + 2 * WT_B);
  float* outp = (float*)d_out;

  mask_kadd<<<BATCH * SEQ / 256, 256, 0, stream>>>(masks, kaddG);
  dim3 tgrid(HID / 32, HID / 32, 3), tblk(32, 8);
  transpose768x3<<<tgrid, tblk, 0, stream>>>(Wq, Wk, Wv, WtQ);

  if (ws_size >= TIER_A_NEED) {
    __bf16* Kf = (__bf16*)(ws + KADD_B + 3 * WT_B);
    __bf16* Vtf = (__bf16*)(ws + KADD_B + 3 * WT_B + KV_FULL_B);
    dim3 pgrid(BATCH * SEQ / 32, NHEADS);
    proj_kv<<<pgrid, 64, 0, stream>>>(toks, WtK, bk, WtV, bv, Kf, Vtf, 0, NHEADS);
    // 1-D swizzled grid: gid = qtile*48 + bh -> same-bh blocks on one XCD
    attn_fused<<<(SEQ / 32) * BATCH * NHEADS, 64, 0, stream>>>(
        toks, WtQ, bq, Kf, Vtf, kaddG, outp, 0, NHEADS);
  } else {
    __bf16* Kh = (__bf16*)(ws + KADD_B + 3 * WT_B);
    __bf16* Vth = (__bf16*)(ws + KADD_B + 3 * WT_B + KV_HEAD_B);
    dim3 pgrid(BATCH * SEQ / 32, 1);
    dim3 agrid(SEQ / 32, 1, BATCH);
    for (int h = 0; h < NHEADS; ++h) {
      proj_kv<<<pgrid, 64, 0, stream>>>(toks, WtK, bk, WtV, bv, Kh, Vth, h, 1);
      attn_fused<<<agrid, 64, 0, stream>>>(toks, WtQ, bq, Kh, Vth, kaddG, outp, h, 1);
    }
  }
}

// Round 10
// 359.870 us; speedup vs baseline: 1.2909x; 1.2909x over previous
//
#include <hip/hip_runtime.h>
#include <hip/hip_bf16.h>
#include <cstddef>

// MHAttention forward, MI355X/gfx950.
// Dtype contract (R0-R3): inputs fp32 (toks, W*, b*; masks int32), OUTPUT fp32.
// Internals: bf16 MFMA fragments, fp32 accumulation.
// R9 -> R10: attn invariant at ~298us across 4 schedules = per-wave private K/V
// loads at L3 latency, latency x concurrency bound (1.66 GB vector traffic,
// ~11k cy per 32-key iter vs ~1k cy issue). Fix = m97 pattern: 256-thread
// blocks, 64q x 64k tiles, K/V staged in LDS (double-buffered, 2 barriers/iter),
// shared by 4 waves (4x less global traffic, batched + decoupled loads).
// Wave roles: wave w does QK^T for key-block w and PV for d-block w.

typedef __bf16 bf16_8 __attribute__((ext_vector_type(8)));
typedef float f32x4 __attribute__((ext_vector_type(4)));
typedef short s16x4 __attribute__((ext_vector_type(4)));
typedef short s16x8 __attribute__((ext_vector_type(8)));

#define HID 768
#define NHEADS 12
#define HD 64
#define BATCH 4
#define SEQ 2048
#define NEGBIG2 (-1.44269504e31f)  // -1e31 * log2e, exp2 -> 0
#define SCALE2 0.18033688f         // 0.125 * log2e

#define KT 64        // keys per LDS tile
#define NKT (SEQ / KT)
#define STR 68       // LDS row stride (elems): 136B rows, 8B-aligned, <=4-way

static __device__ __forceinline__ f32x4 mfma16x16x32(bf16_8 a, bf16_8 b, f32x4 c) {
  return __builtin_amdgcn_mfma_f32_16x16x32_bf16(a, b, c, 0, 0, 0);
}

static __device__ __forceinline__ float fast_exp2(float x) {
#if __has_builtin(__builtin_amdgcn_exp2f)
  return __builtin_amdgcn_exp2f(x);
#else
  return __expf(x * 0.69314718f);
#endif
}

static __device__ __forceinline__ s16x4 pack_bf16x4(f32x4 p) {
  s16x4 o;
#pragma unroll
  for (int i = 0; i < 4; ++i) {
    __bf16 b = (__bf16)p[i];
    o[i] = __builtin_bit_cast(short, b);
  }
  return o;
}

// two b64 LDS reads -> one bf16_8 fragment
static __device__ __forceinline__ bf16_8 cat2(const __bf16* p) {
  s16x4 lo = *(const s16x4*)p;
  s16x4 hi = *(const s16x4*)(p + 4);
  s16x8 v = __builtin_shufflevector(lo, hi, 0, 1, 2, 3, 4, 5, 6, 7);
  return __builtin_bit_cast(bf16_8, v);
}

// one 16B register chunk -> two b64 LDS writes
static __device__ __forceinline__ void write2(__bf16* p, s16x8 v) {
  *(s16x4*)p = __builtin_shufflevector(v, v, 0, 1, 2, 3);
  *(s16x4*)(p + 4) = __builtin_shufflevector(v, v, 4, 5, 6, 7);
}

static __device__ __forceinline__ bf16_8 cvt_a_frag(const float* p) {
  f32x4 af0 = *(const f32x4*)p;
  f32x4 af1 = *(const f32x4*)(p + 4);
  bf16_8 a;
  a[0] = (__bf16)af0[0]; a[1] = (__bf16)af0[1];
  a[2] = (__bf16)af0[2]; a[3] = (__bf16)af0[3];
  a[4] = (__bf16)af1[0]; a[5] = (__bf16)af1[1];
  a[6] = (__bf16)af1[2]; a[7] = (__bf16)af1[3];
  return a;
}

// ---------- mask -> additive kadd2 (0 or -1e31*log2e), fp32, global ----------
__global__ __launch_bounds__(256) void mask_kadd(const int* __restrict__ masks,
                                                 float* __restrict__ kaddG) {
  int i = blockIdx.x * 256 + threadIdx.x;
  kaddG[i] = masks[i] ? 0.0f : NEGBIG2;
}

// ---------- 3x 768x768 transpose + fp32->bf16, one launch (z picks matrix) ----------
__global__ __launch_bounds__(256) void transpose768x3(const float* __restrict__ Wq,
                                                      const float* __restrict__ Wk,
                                                      const float* __restrict__ Wv,
                                                      __bf16* __restrict__ WtBase) {
  const float* in = blockIdx.z == 0 ? Wq : (blockIdx.z == 1 ? Wk : Wv);
  __bf16* out = WtBase + (size_t)blockIdx.z * HID * HID;
  __shared__ __bf16 tile[32][33];
  int bx = blockIdx.x * 32, by = blockIdx.y * 32;
  int tx = threadIdx.x, ty = threadIdx.y;  // block (32,8)
#pragma unroll
  for (int r = 0; r < 32; r += 8)
    tile[ty + r][tx] = (__bf16)in[(size_t)(by + ty + r) * HID + bx + tx];
  __syncthreads();
#pragma unroll
  for (int r = 0; r < 32; r += 8)
    out[(size_t)(bx + ty + r) * HID + by + tx] = tile[tx][ty + r];
}

// ---------- K+V projection fused: one wave -> 32 rows x 64 cols, both K and V ----------
__global__ __launch_bounds__(64) void proj_kv(const float* __restrict__ toks,
                                              const __bf16* __restrict__ WtK,
                                              const float* __restrict__ bk,
                                              const __bf16* __restrict__ WtV,
                                              const float* __restrict__ bv,
                                              __bf16* __restrict__ Kout,
                                              __bf16* __restrict__ Vtout,
                                              int head0, int hm) {
  int lane = threadIdx.x, l16 = lane & 15, quad = lane >> 4;
  int m0 = blockIdx.x * 32;
  int hl = blockIdx.y, h = head0 + hl;
  const float* arow0 = toks + (size_t)(m0 + l16) * HID + quad * 8;
  const float* arow1 = arow0 + (size_t)16 * HID;
  const __bf16* bKrow = WtK + (size_t)(h * 64 + l16) * HID + quad * 8;
  const __bf16* bVrow = WtV + (size_t)(h * 64 + l16) * HID + quad * 8;
  f32x4 zero = {0.f, 0.f, 0.f, 0.f};
  f32x4 aK[2][4], aV[2][4];
#pragma unroll
  for (int g = 0; g < 2; ++g)
#pragma unroll
    for (int t = 0; t < 4; ++t) { aK[g][t] = zero; aV[g][t] = zero; }
  for (int kk = 0; kk < HID; kk += 32) {
    bf16_8 a0 = cvt_a_frag(arow0 + kk);
    bf16_8 a1 = cvt_a_frag(arow1 + kk);
#pragma unroll
    for (int t = 0; t < 4; ++t) {
      bf16_8 bkf = *(const bf16_8*)(bKrow + (size_t)t * 16 * HID + kk);
      bf16_8 bvf = *(const bf16_8*)(bVrow + (size_t)t * 16 * HID + kk);
      aK[0][t] = mfma16x16x32(a0, bkf, aK[0][t]);
      aK[1][t] = mfma16x16x32(a1, bkf, aK[1][t]);
      aV[0][t] = mfma16x16x32(a0, bvf, aV[0][t]);
      aV[1][t] = mfma16x16x32(a1, bvf, aV[1][t]);
    }
  }
#pragma unroll
  for (int g = 0; g < 2; ++g)
#pragma unroll
    for (int t = 0; t < 4; ++t) {
      int d = t * 16 + l16;
      float bnK = bk[h * 64 + d];
      float bnV = bv[h * 64 + d];
#pragma unroll
      for (int r = 0; r < 4; ++r) {
        int m = m0 + g * 16 + quad * 4 + r;
        int b = m >> 11;
        int s = m & (SEQ - 1);
        Kout[(((size_t)b * hm + hl) * SEQ + s) * HD + d] = (__bf16)(aK[g][t][r] + bnK);
        Vtout[(((size_t)b * hm + hl) * HD + d) * SEQ + s] = (__bf16)(aV[g][t][r] + bnV);
      }
    }
}

// ---------- fused Q-proj + flash attention, m97-style LDS staging ----------
// Block 256 threads (4 waves) per (bh, 64-query tile). 64-key K/V tiles staged
// in double-buffered LDS, shared by all waves. Wave w: Q-proj for qsub w;
// QK^T (S^T = K*Q^T) for key-block w vs ALL 64 q; PV for d-block w vs all q.
// P and lsum cross waves via LDS under the 2 per-iter barriers.
__global__ __launch_bounds__(256) void attn_fused(const float* __restrict__ toks,
                                                  const __bf16* __restrict__ WtQ,
                                                  const float* __restrict__ bq,
                                                  const __bf16* __restrict__ Kbuf,
                                                  const __bf16* __restrict__ Vtbuf,
                                                  const float* __restrict__ kaddG,
                                                  float* __restrict__ out,
                                                  int head0, int hm) {
  __shared__ __align__(16) __bf16 ldsK[2][64 * STR];  // 17408 B
  __shared__ __align__(16) __bf16 ldsV[2][64 * STR];  // 17408 B
  __shared__ __align__(16) __bf16 ldsQ[64 * STR];     // 8704 B
  __shared__ __align__(16) __bf16 ldsP[64 * STR];     // 8704 B  (total 52224)
  int tid = threadIdx.x;
  int w = tid >> 6, lane = tid & 63, l16 = lane & 15, quad = lane >> 4;
  int bz = blockIdx.z, hl = blockIdx.y, h = head0 + hl;
  int q0 = blockIdx.x * 64;
  const float* kb = kaddG + (size_t)bz * SEQ;
  f32x4 zero = {0.f, 0.f, 0.f, 0.f};

  const __bf16* Kb = Kbuf + ((size_t)bz * hm + hl) * SEQ * HD;
  const __bf16* Vb = Vtbuf + ((size_t)bz * hm + hl) * HD * SEQ;

  // --- Q projection: wave w -> rows q0 + w*16 .. +16, all 64 d ---
  {
    const float* arow = toks + ((size_t)bz * SEQ + q0 + w * 16 + l16) * HID + quad * 8;
    const __bf16* brow = WtQ + (size_t)(h * 64 + l16) * HID + quad * 8;
    f32x4 qa[4] = {zero, zero, zero, zero};
    for (int kk = 0; kk < HID; kk += 32) {
      bf16_8 a = cvt_a_frag(arow + kk);
#pragma unroll
      for (int t = 0; t < 4; ++t)
        qa[t] = mfma16x16x32(a, *(const bf16_8*)(brow + (size_t)t * 16 * HID + kk), qa[t]);
    }
#pragma unroll
    for (int t = 0; t < 4; ++t) {
      float bn = bq[h * 64 + t * 16 + l16];
#pragma unroll
      for (int r = 0; r < 4; ++r)
        ldsQ[(w * 16 + quad * 4 + r) * STR + t * 16 + l16] = (__bf16)(qa[t][r] + bn);
    }
  }

  // --- stage tile 0 (K rows = keys, V rows = d; 16B/chunk, 4 chunks/thread) ---
  int srow = tid >> 3, sc = tid & 7;  // srow 0..31, chunk 0..7
  {
    s16x8 k0 = *(const s16x8*)(Kb + (size_t)srow * HD + sc * 8);
    s16x8 k1 = *(const s16x8*)(Kb + (size_t)(srow + 32) * HD + sc * 8);
    s16x8 v0 = *(const s16x8*)(Vb + (size_t)srow * SEQ + sc * 8);
    s16x8 v1 = *(const s16x8*)(Vb + (size_t)(srow + 32) * SEQ + sc * 8);
    write2(&ldsK[0][srow * STR + sc * 8], k0);
    write2(&ldsK[0][(srow + 32) * STR + sc * 8], k1);
    write2(&ldsV[0][srow * STR + sc * 8], v0);
    write2(&ldsV[0][(srow + 32) * STR + sc * 8], v1);
  }
  __syncthreads();  // Q + tile 0 visible

  // Q B-frags for ALL 4 q-subtiles: lane holds Q[q = s*16+l16][d = half*32+quad*8+j]
  bf16_8 qf[4][2];
#pragma unroll
  for (int s = 0; s < 4; ++s)
#pragma unroll
    for (int half = 0; half < 2; ++half)
      qf[s][half] = cat2(&ldsQ[(s * 16 + l16) * STR + half * 32 + quad * 8]);

  // query-row activity per qsub (q = s*16 + l16): 1 normal, 0 -> all-zero logits (= ref)
  float actq[4];
#pragma unroll
  for (int s = 0; s < 4; ++s) actq[s] = (kb[q0 + s * 16 + l16] == 0.0f) ? 1.0f : 0.0f;

  float lsum[4] = {0.f, 0.f, 0.f, 0.f};
  f32x4 acc[4];
#pragma unroll
  for (int s = 0; s < 4; ++s) acc[s] = zero;

  for (int t = 0; t < NKT; ++t) {
    int j0 = t * KT;
    int jn = (t + 1 < NKT) ? j0 + KT : 0;  // wrap: valid addr, values unused
    int buf = t & 1, nbuf = buf ^ 1;
    // stage loads for t+1 (consumed by ds_write at the bottom -> full-iter slack)
    s16x8 k0 = *(const s16x8*)(Kb + (size_t)(jn + srow) * HD + sc * 8);
    s16x8 k1 = *(const s16x8*)(Kb + (size_t)(jn + srow + 32) * HD + sc * 8);
    s16x8 v0 = *(const s16x8*)(Vb + (size_t)srow * SEQ + jn + sc * 8);
    s16x8 v1 = *(const s16x8*)(Vb + (size_t)(srow + 32) * SEQ + jn + sc * 8);

    // --- QK^T for this wave's key block (keys j0 + w*16 .. +16) vs all 64 q ---
    bf16_8 kf[2];
#pragma unroll
    for (int half = 0; half < 2; ++half)
      kf[half] = cat2(&ldsK[buf][(w * 16 + l16) * STR + half * 32 + quad * 8]);
    f32x4 ck = *(const f32x4*)(kb + j0 + w * 16 + quad * 4);  // mask for key=..+quad*4+r
#pragma unroll
    for (int s = 0; s < 4; ++s) {
      // S^T tile: lane holds S^T[key = w*16 + quad*4 + r][q = s*16 + l16]
      f32x4 st = mfma16x16x32(kf[1], qf[s][1], mfma16x16x32(kf[0], qf[s][0], zero));
      f32x4 p;
#pragma unroll
      for (int r = 0; r < 4; ++r) {
        // masked key: fma -> -1.44e31, exp2 -> 0. inactive q: actq=0 -> logit 0.
        float v = actq[s] * fmaf(st[r], SCALE2, ck[r]);
        p[r] = fast_exp2(v);
      }
      lsum[s] += p[0] + p[1] + p[2] + p[3];
      // P[q = s*16+l16][key-local = w*16 + quad*4 .. +4] -> one b64 store
      *(s16x4*)(&ldsP[(s * 16 + l16) * STR + w * 16 + quad * 4]) = pack_bf16x4(p);
    }
    __syncthreads();  // B1: P complete (all key blocks), K reads done

    // --- PV for this wave's d block (d = w*16 .. +16) vs all 64 keys ---
#pragma unroll
    for (int kc = 0; kc < 2; ++kc) {
      // V B-frag: lane holds Vt[d = w*16 + l16][k = kc*32 + quad*8 + j]
      bf16_8 vf = cat2(&ldsV[buf][(w * 16 + l16) * STR + kc * 32 + quad * 8]);
#pragma unroll
      for (int s = 0; s < 4; ++s) {
        // P A-frag: lane holds P[q = s*16 + l16][k = kc*32 + quad*8 + j]
        bf16_8 pf = cat2(&ldsP[(s * 16 + l16) * STR + kc * 32 + quad * 8]);
        acc[s] = mfma16x16x32(pf, vf, acc[s]);
      }
    }
    // stage-write t+1 into the other buffer (WAR safe: its readers finished pre-B1(t-1))
    write2(&ldsK[nbuf][srow * STR + sc * 8], k0);
    write2(&ldsK[nbuf][(srow + 32) * STR + sc * 8], k1);
    write2(&ldsV[nbuf][srow * STR + sc * 8], v0);
    write2(&ldsV[nbuf][(srow + 32) * STR + sc * 8], v1);
    __syncthreads();  // B2: tile t+1 visible; P free for overwrite
  }

  // --- lsum: quad-sum in-wave, then cross-wave via LDS (ldsP reused, post-B2) ---
  float* ls = (float*)ldsP;
#pragma unroll
  for (int s = 0; s < 4; ++s) {
    float v = lsum[s];
    v += __shfl_xor(v, 16);
    v += __shfl_xor(v, 32);
    if (quad == 0) ls[(w * 4 + s) * 16 + l16] = v;  // per (wave, qsub, q=l16)
  }
  __syncthreads();
  float lr[4][4];
#pragma unroll
  for (int s = 0; s < 4; ++s) {
    float tot = ls[(0 * 4 + s) * 16 + l16] + ls[(1 * 4 + s) * 16 + l16] +
                ls[(2 * 4 + s) * 16 + l16] + ls[(3 * 4 + s) * 16 + l16];
    float linv = 1.0f / tot;
#pragma unroll
    for (int r = 0; r < 4; ++r) lr[s][r] = __shfl(linv, quad * 4 + r);  // q = quad*4+r
  }
#pragma unroll
  for (int s = 0; s < 4; ++s)
#pragma unroll
    for (int r = 0; r < 4; ++r)
      out[((size_t)bz * SEQ + q0 + s * 16 + quad * 4 + r) * HID + h * HD + w * 16 + l16] =
          acc[s][r] * lr[s][r];
}

extern "C" void kernel_launch(void* const* d_in, const int* in_sizes, int n_in,
                              void* d_out, int out_size, void* d_ws, size_t ws_size,
                              hipStream_t stream) {
  (void)in_sizes; (void)n_in; (void)out_size;
  const float* toks = (const float*)d_in[0];
  const int* masks = (const int*)d_in[1];
  const float* Wq = (const float*)d_in[2];
  const float* bq = (const float*)d_in[3];
  const float* Wk = (const float*)d_in[4];
  const float* bk = (const float*)d_in[5];
  const float* Wv = (const float*)d_in[6];
  const float* bv = (const float*)d_in[7];
  char* ws = (char*)d_ws;
  const size_t KADD_B = (size_t)BATCH * SEQ * 4;
  const size_t WT_B = (size_t)HID * HID * 2;
  const size_t KV_FULL_B = (size_t)BATCH * NHEADS * SEQ * HD * 2;
  const size_t KV_HEAD_B = (size_t)BATCH * SEQ * HD * 2;
  const size_t TIER_A_NEED = KADD_B + 3 * WT_B + 2 * KV_FULL_B;  // ~28.7 MB
  float* kaddG = (float*)(ws);
  __bf16* WtQ = (__bf16*)(ws + KADD_B + 0 * WT_B);
  __bf16* WtK = (__bf16*)(ws + KADD_B + 1 * WT_B);
  __bf16* WtV = (__bf16*)(ws + KADD_B + 2 * WT_B);
  float* outp = (float*)d_out;

  mask_kadd<<<BATCH * SEQ / 256, 256, 0, stream>>>(masks, kaddG);
  dim3 tgrid(HID / 32, HID / 32, 3), tblk(32, 8);
  transpose768x3<<<tgrid, tblk, 0, stream>>>(Wq, Wk, Wv, WtQ);

  if (ws_size >= TIER_A_NEED) {
    __bf16* Kf = (__bf16*)(ws + KADD_B + 3 * WT_B);
    __bf16* Vtf = (__bf16*)(ws + KADD_B + 3 * WT_B + KV_FULL_B);
    dim3 pgrid(BATCH * SEQ / 32, NHEADS);
    proj_kv<<<pgrid, 64, 0, stream>>>(toks, WtK, bk, WtV, bv, Kf, Vtf, 0, NHEADS);
    dim3 agrid(SEQ / 64, NHEADS, BATCH);
    attn_fused<<<agrid, 256, 0, stream>>>(toks, WtQ, bq, Kf, Vtf, kaddG, outp, 0, NHEADS);
  } else {
    __bf16* Kh = (__bf16*)(ws + KADD_B + 3 * WT_B);
    __bf16* Vth = (__bf16*)(ws + KADD_B + 3 * WT_B + KV_HEAD_B);
    dim3 pgrid(BATCH * SEQ / 32, 1);
    dim3 agrid(SEQ / 64, 1, BATCH);
    for (int h = 0; h < NHEADS; ++h) {
      proj_kv<<<pgrid, 64, 0, stream>>>(toks, WtK, bk, WtV, bv, Kh, Vth, h, 1);
      attn_fused<<<agrid, 256, 0, stream>>>(toks, WtQ, bq, Kh, Vth, kaddG, outp, h, 1);
    }
  }
}